// Round 1
// baseline (247.655 us; speedup 1.0000x reference)
//
#include <hip/hip_runtime.h>
#include <stdint.h>

typedef unsigned long long u64;

#define FACTOR 6.26f
#define D      2048
#define TPB    256
#define CAP    256
#define THRESH 1.5f

__device__ __forceinline__ u64 kmax64(u64 a, u64 b) { return a > b ? a : b; }

__device__ __forceinline__ u64 wave_max64(u64 c) {
#pragma unroll
    for (int d = 1; d < 64; d <<= 1) {
        u64 o = __shfl_xor(c, d, 64);
        c = (c > o) ? c : o;
    }
    return c;
}

// Extract top-32 keys from a compacted candidate list (cnt entries, cnt>=32, cnt<=CAP).
// Keys: (float_bits(value)<<32) | (2047 - idx); value>THRESH>0 so all keys nonzero.
// Strictly-decreasing "prev" filter avoids any mutation of the list.
__device__ void extract32_list(const u64* __restrict__ list, int cnt,
                               u64* wins, float* topsum, int lane) {
    u64 k0 = (lane       < cnt) ? list[lane]       : 0;
    u64 k1 = (lane + 64  < cnt) ? list[lane + 64]  : 0;
    u64 k2 = (lane + 128 < cnt) ? list[lane + 128] : 0;
    u64 k3 = (lane + 192 < cnt) ? list[lane + 192] : 0;
    u64 prev = ~0ull;
    float tsum = 0.f;
    for (int it = 0; it < 32; ++it) {
        u64 c = 0, q;
        q = (k0 < prev) ? k0 : 0; c = kmax64(c, q);
        q = (k1 < prev) ? k1 : 0; c = kmax64(c, q);
        q = (k2 < prev) ? k2 : 0; c = kmax64(c, q);
        q = (k3 < prev) ? k3 : 0; c = kmax64(c, q);
        c = wave_max64(c);
        prev = c;
        tsum += __uint_as_float((unsigned)(c >> 32));
        if (lane == it) wins[it] = c;
    }
    if (lane == 0) *topsum = tsum;
}

// Exact fallback: top-32 over the full LDS row (statistically never taken).
// sign=+1: top of relu(x); sign=-1: top of relu(-x). Handles degenerate rows
// (fewer than 32 strictly-signed elements) with jax tie-break (smallest index).
__device__ void extract32_row(const float* __restrict__ s_row, int sign,
                              u64* wins, float* topsum, int lane) {
    u64 prev = ~0ull;
    float tsum = 0.f;
    for (int it = 0; it < 32; ++it) {
        u64 c = 0;
        for (int j = 0; j < 32; ++j) {
            int idx = j * 64 + lane;
            float xv = s_row[idx];
            float pv = (sign > 0) ? ((xv > 0.f) ? xv : 0.f)
                                  : ((xv < 0.f) ? -xv : 0.f);
            u64 k = ((u64)__float_as_uint(pv) << 32) | (u64)(unsigned)(2047 - idx);
            u64 q = (k < prev) ? k : 0;
            c = kmax64(c, q);
        }
        c = wave_max64(c);
        prev = c;
        tsum += __uint_as_float((unsigned)(c >> 32));
        if (lane == it) wins[it] = c;
    }
    if (lane == 0) *topsum = tsum;
}

__global__ void __launch_bounds__(TPB)
kcomp_kernel(const float* __restrict__ x, float* __restrict__ out) {
    __shared__ float s_row[D];
    __shared__ u64   s_listP[CAP], s_listN[CAP];
    __shared__ u64   s_winP[32], s_winN[32];
    __shared__ float s_psum[4], s_nsum[4];
    __shared__ float s_topP, s_topN;
    __shared__ int   s_cntP, s_cntN;

    const int t    = threadIdx.x;
    const int lane = t & 63;
    const int wave = t >> 6;
    const size_t rbase = (size_t)blockIdx.x * D;

    if (t == 0) { s_cntP = 0; s_cntN = 0; }
    __syncthreads();

    const float4* xr = reinterpret_cast<const float4*>(x + rbase);
    float4 a = xr[t];
    float4 b = xr[t + TPB];
    reinterpret_cast<float4*>(s_row)[t]       = a;
    reinterpret_cast<float4*>(s_row)[t + TPB] = b;

    float ps = 0.f, ns = 0.f;
    float va[8] = {a.x, a.y, a.z, a.w, b.x, b.y, b.z, b.w};
#pragma unroll
    for (int j = 0; j < 8; ++j) {
        int idx = (j < 4) ? (4 * t + j) : (4 * TPB + 4 * t + (j - 4));
        float v = va[j];
        ps += (v > 0.f) ? v : 0.f;
        ns += (v < 0.f) ? -v : 0.f;
        if (v > THRESH) {
            int p = atomicAdd(&s_cntP, 1);
            if (p < CAP)
                s_listP[p] = ((u64)__float_as_uint(v) << 32) | (u64)(unsigned)(2047 - idx);
        }
        if (v < -THRESH) {
            int p = atomicAdd(&s_cntN, 1);
            if (p < CAP)
                s_listN[p] = ((u64)__float_as_uint(-v) << 32) | (u64)(unsigned)(2047 - idx);
        }
    }
    // wave-level sum reduce, then per-wave partials to LDS
#pragma unroll
    for (int d2 = 1; d2 < 64; d2 <<= 1) {
        ps += __shfl_xor(ps, d2, 64);
        ns += __shfl_xor(ns, d2, 64);
    }
    if (lane == 0) { s_psum[wave] = ps; s_nsum[wave] = ns; }
    __syncthreads();

    const int cP = s_cntP, cN = s_cntN;
    if (wave == 0) {
        if (cP >= 32 && cP <= CAP) extract32_list(s_listP, cP, s_winP, &s_topP, lane);
        else                       extract32_row(s_row, +1, s_winP, &s_topP, lane);
    } else if (wave == 1) {
        if (cN >= 32 && cN <= CAP) extract32_list(s_listN, cN, s_winN, &s_topN, lane);
        else                       extract32_row(s_row, -1, s_winN, &s_topN, lane);
    }
    __syncthreads();

    // reuse s_row as the output staging buffer: zero it
    float4 z = make_float4(0.f, 0.f, 0.f, 0.f);
    reinterpret_cast<float4*>(s_row)[t]       = z;
    reinterpret_cast<float4*>(s_row)[t + TPB] = z;
    __syncthreads();

    if (t < 32) {
        float sumP = s_psum[0] + s_psum[1] + s_psum[2] + s_psum[3];
        float Ptmp = FACTOR * (sumP - s_topP);
        u64 k = s_winP[t];
        int idx = 2047 - (int)(unsigned)(k & 0xffffffffu);
        s_row[idx] = __uint_as_float((unsigned)(k >> 32)) + Ptmp;
    } else if (t < 64) {
        float sumN = s_nsum[0] + s_nsum[1] + s_nsum[2] + s_nsum[3];
        float Ntmp = FACTOR * (sumN - s_topN);
        u64 k = s_winN[t - 32];
        int idx = 2047 - (int)(unsigned)(k & 0xffffffffu);
        s_row[idx] = -(__uint_as_float((unsigned)(k >> 32)) + Ntmp);
    }
    __syncthreads();

    float4* orow = reinterpret_cast<float4*>(out + rbase);
    orow[t]       = reinterpret_cast<const float4*>(s_row)[t];
    orow[t + TPB] = reinterpret_cast<const float4*>(s_row)[t + TPB];
}

extern "C" void kernel_launch(void* const* d_in, const int* in_sizes, int n_in,
                              void* d_out, int out_size, void* d_ws, size_t ws_size,
                              hipStream_t stream) {
    const float* x = (const float*)d_in[0];
    float* out = (float*)d_out;
    const int rows = in_sizes[0] / D;  // 16384
    kcomp_kernel<<<rows, TPB, 0, stream>>>(x, out);
}

// Round 2
// 96.481 us; speedup vs baseline: 2.5669x; 2.5669x over previous
//
#include <hip/hip_runtime.h>
#include <stdint.h>

typedef unsigned int u32;
typedef unsigned long long u64;

#define FACTOR  6.26f
#define D       2048
#define TPB     256
#define WPB     4       // one row per wave
#define CAP     256     // per-side candidate list capacity
#define TH      1.5f
#define TH_BITS 0x3FC00000u   // __float_as_uint(1.5f)

__device__ __forceinline__ float wsum_f(float v) {
#pragma unroll
    for (int d = 1; d < 64; d <<= 1) v += __shfl_xor(v, d, 64);
    return v;
}
__device__ __forceinline__ u32 wsum_u(u32 v) {
#pragma unroll
    for (int d = 1; d < 64; d <<= 1) v += __shfl_xor(v, d, 64);
    return v;
}
__device__ __forceinline__ u32 wmin_u(u32 v) {
#pragma unroll
    for (int d = 1; d < 64; d <<= 1) { u32 o = __shfl_xor(v, d, 64); v = o < v ? o : v; }
    return v;
}

// Bisection with counts over a compacted LDS list (4 reg slots/lane, ballot counts).
__device__ __forceinline__ u32 bisect_list(u32 k0, u32 k1, u32 k2, u32 k3) {
    u32 lo = TH_BITS, hi = 0x7F800001u;
    while (hi - lo > 1u) {
        u32 mid = lo + ((hi - lo) >> 1);
        int c = __popcll(__ballot(k0 >= mid)) + __popcll(__ballot(k1 >= mid))
              + __popcll(__ballot(k2 >= mid)) + __popcll(__ballot(k3 >= mid));
        if (c >= 32) { lo = mid; if (c == 32) break; } else hi = mid;
    }
    return lo;
}

__global__ void __launch_bounds__(TPB)
kcomp_kernel(const float* __restrict__ x, float* __restrict__ out) {
    __shared__ u32 s_list[WPB][2][CAP];

    const int t    = threadIdx.x;
    const int lane = t & 63;
    const int wave = t >> 6;
    const size_t rbase = (size_t)(blockIdx.x * WPB + wave) * D;

    const float4* xr = reinterpret_cast<const float4*>(x + rbase);

    // ---- load row: lane holds elements flat = q*256 + lane*4 + c, q=0..7, c=0..3
    float rv[32];
#pragma unroll
    for (int q = 0; q < 8; ++q) {
        float4 f = xr[q * 64 + lane];
        rv[q * 4 + 0] = f.x; rv[q * 4 + 1] = f.y;
        rv[q * 4 + 2] = f.z; rv[q * 4 + 3] = f.w;
    }

    // ---- per-lane sums and candidate counts
    float ps = 0.f, ns = 0.f; u32 cP = 0, cN = 0;
#pragma unroll
    for (int e = 0; e < 32; ++e) {
        float v = rv[e];
        ps += (v > 0.f) ? v : 0.f;
        ns += (v < 0.f) ? -v : 0.f;
        cP += (v > TH)  ? 1u : 0u;
        cN += (v < -TH) ? 1u : 0u;
    }

    // packed inclusive prefix scan (Hillis-Steele) for compaction offsets
    u32 packed = cP | (cN << 16);
    u32 inc = packed;
#pragma unroll
    for (int d = 1; d < 64; d <<= 1) {
        u32 n = __shfl_up(inc, (unsigned)d, 64);
        if (lane >= d) inc += n;
    }
    u32 tot  = __shfl(inc, 63, 64);
    u32 exc  = inc - packed;
    u32 totP = tot & 0xffffu, totN = tot >> 16;
    u32 offP = exc & 0xffffu, offN = exc >> 16;

    float sumP = wsum_f(ps), sumN = wsum_f(ns);

    const bool fastP = (totP >= 32u && totP <= CAP);
    const bool fastN = (totN >= 32u && totN <= CAP);
    u32* listP = s_list[wave][0];
    u32* listN = s_list[wave][1];

#pragma unroll
    for (int e = 0; e < 32; ++e) {
        float v = rv[e];
        if (fastP && v > TH)  listP[offP++] = __float_as_uint(v);
        if (fastN && v < -TH) listN[offN++] = __float_as_uint(-v);
    }

    // ---- find cut T* for each side
    u32 TstarP, TstarN;
    if (fastP) {
        u32 k0 = (lane       < (int)totP) ? listP[lane]       : 0u;
        u32 k1 = (lane + 64  < (int)totP) ? listP[lane + 64]  : 0u;
        u32 k2 = (lane + 128 < (int)totP) ? listP[lane + 128] : 0u;
        u32 k3 = (lane + 192 < (int)totP) ? listP[lane + 192] : 0u;
        TstarP = bisect_list(k0, k1, k2, k3);
    } else {
        // exact slow path: bisect with register-scan counts over keyP = bits(max(v,0))
        u32 lo = 0u, hi = 0x7F800001u;
        while (hi - lo > 1u) {
            u32 mid = lo + ((hi - lo) >> 1);
            u32 cl = 0;
#pragma unroll
            for (int e = 0; e < 32; ++e) {
                float v = rv[e]; float pv = (v > 0.f) ? v : 0.f;
                cl += (__float_as_uint(pv) >= mid) ? 1u : 0u;
            }
            u32 c = wsum_u(cl);
            if (c >= 32) { lo = mid; if (c == 32) break; } else hi = mid;
        }
        TstarP = lo;
    }
    if (fastN) {
        u32 k0 = (lane       < (int)totN) ? listN[lane]       : 0u;
        u32 k1 = (lane + 64  < (int)totN) ? listN[lane + 64]  : 0u;
        u32 k2 = (lane + 128 < (int)totN) ? listN[lane + 128] : 0u;
        u32 k3 = (lane + 192 < (int)totN) ? listN[lane + 192] : 0u;
        TstarN = bisect_list(k0, k1, k2, k3);
    } else {
        u32 lo = 0u, hi = 0x7F800001u;
        while (hi - lo > 1u) {
            u32 mid = lo + ((hi - lo) >> 1);
            u32 cl = 0;
#pragma unroll
            for (int e = 0; e < 32; ++e) {
                float v = rv[e]; float nv = (v < 0.f) ? -v : 0.f;
                cl += (__float_as_uint(nv) >= mid) ? 1u : 0u;
            }
            u32 c = wsum_u(cl);
            if (c >= 32) { lo = mid; if (c == 32) break; } else hi = mid;
        }
        TstarN = lo;
    }

    // ---- P epilogue: winner set + top-sum (tie-exact)
    u32 cgt = 0, ceq = 0;
#pragma unroll
    for (int e = 0; e < 32; ++e) {
        float v = rv[e]; float pv = (v > 0.f) ? v : 0.f; u32 b = __float_as_uint(pv);
        cgt += (b > TstarP) ? 1u : 0u;
        ceq += (b == TstarP) ? 1u : 0u;
    }
    u32 pk = wsum_u(cgt | (ceq << 16));
    u32 c1 = pk & 0xffffu, meq = pk >> 16;
    u32 fill = 32u - c1;
    u32 chosenP;
    if (meq == fill) {
        chosenP = 0xFFFFFFFFu;  // every ==T* element wins
    } else {
        chosenP = 0u;           // rare: index tie-break, pick `fill` smallest flat idx
        for (u32 s = 0; s < fill; ++s) {
            u32 best = 0xFFFFFFFFu; int beste = -1;
#pragma unroll
            for (int e = 0; e < 32; ++e) {
                float v = rv[e]; float pv = (v > 0.f) ? v : 0.f;
                if (__float_as_uint(pv) == TstarP && !((chosenP >> e) & 1u)) {
                    u32 fi = (u32)((e >> 2) * 256 + lane * 4 + (e & 3));
                    if (fi < best) { best = fi; beste = e; }
                }
            }
            u32 m = wmin_u(best);
            if (best == m && beste >= 0 && m != 0xFFFFFFFFu) chosenP |= (1u << beste);
        }
    }
    float tsP = 0.f; u32 winP = 0;
#pragma unroll
    for (int e = 0; e < 32; ++e) {
        float v = rv[e]; float pv = (v > 0.f) ? v : 0.f; u32 b = __float_as_uint(pv);
        bool w = (b > TstarP) || (b == TstarP && ((chosenP >> e) & 1u));
        if (w) { winP |= (1u << e); tsP += pv; }
    }
    float topP = wsum_f(tsP);
    float Ptmp = FACTOR * (sumP - topP);

    // ---- N epilogue
    cgt = 0; ceq = 0;
#pragma unroll
    for (int e = 0; e < 32; ++e) {
        float v = rv[e]; float nv = (v < 0.f) ? -v : 0.f; u32 b = __float_as_uint(nv);
        cgt += (b > TstarN) ? 1u : 0u;
        ceq += (b == TstarN) ? 1u : 0u;
    }
    pk = wsum_u(cgt | (ceq << 16));
    c1 = pk & 0xffffu; meq = pk >> 16;
    fill = 32u - c1;
    u32 chosenN;
    if (meq == fill) {
        chosenN = 0xFFFFFFFFu;
    } else {
        chosenN = 0u;
        for (u32 s = 0; s < fill; ++s) {
            u32 best = 0xFFFFFFFFu; int beste = -1;
#pragma unroll
            for (int e = 0; e < 32; ++e) {
                float v = rv[e]; float nv = (v < 0.f) ? -v : 0.f;
                if (__float_as_uint(nv) == TstarN && !((chosenN >> e) & 1u)) {
                    u32 fi = (u32)((e >> 2) * 256 + lane * 4 + (e & 3));
                    if (fi < best) { best = fi; beste = e; }
                }
            }
            u32 m = wmin_u(best);
            if (best == m && beste >= 0 && m != 0xFFFFFFFFu) chosenN |= (1u << beste);
        }
    }
    float tsN = 0.f; u32 winN = 0;
#pragma unroll
    for (int e = 0; e < 32; ++e) {
        float v = rv[e]; float nv = (v < 0.f) ? -v : 0.f; u32 b = __float_as_uint(nv);
        bool w = (b > TstarN) || (b == TstarN && ((chosenN >> e) & 1u));
        if (w) { winN |= (1u << e); tsN += nv; }
    }
    float topN = wsum_f(tsN);
    float Ntmp = FACTOR * (sumN - topN);

    // ---- output: out = P_reset - N_reset, built fully in registers, coalesced store
    float4* orow = reinterpret_cast<float4*>(out + rbase);
#pragma unroll
    for (int q = 0; q < 8; ++q) {
        float4 o;
        float vals[4];
#pragma unroll
        for (int c = 0; c < 4; ++c) {
            int e = q * 4 + c;
            float v = rv[e];
            float pv = (v > 0.f) ? v : 0.f;
            float nv = (v < 0.f) ? -v : 0.f;
            float val = 0.f;
            if ((winP >> e) & 1u) val += pv + Ptmp;
            if ((winN >> e) & 1u) val -= nv + Ntmp;
            vals[c] = val;
        }
        o.x = vals[0]; o.y = vals[1]; o.z = vals[2]; o.w = vals[3];
        orow[q * 64 + lane] = o;
    }
}

extern "C" void kernel_launch(void* const* d_in, const int* in_sizes, int n_in,
                              void* d_out, int out_size, void* d_ws, size_t ws_size,
                              hipStream_t stream) {
    const float* x = (const float*)d_in[0];
    float* out = (float*)d_out;
    const int rows = in_sizes[0] / D;       // 16384
    kcomp_kernel<<<rows / WPB, TPB, 0, stream>>>(x, out);
}

// Round 3
// 63.632 us; speedup vs baseline: 3.8920x; 1.5162x over previous
//
#include <hip/hip_runtime.h>
#include <stdint.h>

typedef unsigned int u32;
typedef unsigned long long u64;

#define FACTOR  6.26f
#define D       2048
#define TPB     256
#define WPB     4        // one row per wave
#define CAP     256      // per-side candidate list capacity (mean 137, sd 11)
#define TH      1.5f
#define TH_BITS 0x3FC00000u

// Seeds for the 32nd-largest tail value of 2048 N(0,1): concentrated at 2.15 +/- 0.07.
#define SEED_LO (((u64)0x3FE66666u) << 32)   // 1.80f
#define SEED_HI (((u64)0x402147AEu) << 32)   // 2.52f

__device__ __forceinline__ float wsum_f(float v) {
#pragma unroll
    for (int d = 1; d < 64; d <<= 1) v += __shfl_xor(v, d, 64);
    return v;
}
__device__ __forceinline__ u32 wsum_u(u32 v) {
#pragma unroll
    for (int d = 1; d < 64; d <<= 1) v += __shfl_xor(v, d, 64);
    return v;
}
__device__ __forceinline__ float valof(u64 k) { return __uint_as_float((u32)(k >> 32)); }

__device__ __forceinline__ int cnt4(u64 k0, u64 k1, u64 k2, u64 k3, u64 mid) {
    return __popcll(__ballot(k0 >= mid)) + __popcll(__ballot(k1 >= mid))
         + __popcll(__ballot(k2 >= mid)) + __popcll(__ballot(k3 >= mid));
}

// Exact cut: returns cut with |{k : k >= cut}| == 32.
// Preconditions: keys distinct; exactly tot (32<=tot<=CAP) nonzero keys, all
// > (TH_BITS<<32); empty slots are 0. Seeded bisect, exact for any input.
__device__ __forceinline__ u64 find_cut(u64 k0, u64 k1, u64 k2, u64 k3) {
    u64 lo = ((u64)TH_BITS) << 32;        // count(>=lo) = tot >= 32
    u64 hi = 0xFFFFFFFF00000000ull;       // count(>=hi) = 0
    int c = cnt4(k0, k1, k2, k3, SEED_LO);
    if (c == 32) return SEED_LO;
    if (c > 32) {
        lo = SEED_LO;
        int c2 = cnt4(k0, k1, k2, k3, SEED_HI);
        if (c2 == 32) return SEED_HI;
        if (c2 > 32) lo = SEED_HI; else hi = SEED_HI;
    } else {
        hi = SEED_LO;
    }
    while (hi - lo > 1ull) {
        u64 mid = lo + ((hi - lo) >> 1);
        int cm = cnt4(k0, k1, k2, k3, mid);
        if (cm >= 32) { lo = mid; if (cm == 32) break; } else hi = mid;
    }
    return lo;  // distinct keys => |{k >= lo}| == 32 at both exits
}

// Cold exact fallback (prob ~1e-19 for this data): full-row key bisect with
// per-round global re-read (keeps hot-path registers untouched), atomicAdd
// scatter (handles the only case where P and N winner indices can overlap).
__device__ __attribute__((noinline))
void slow_side(const float4* __restrict__ xr, float* __restrict__ outrow,
               int lane, int neg, float sum) {
    u64 lo = 0ull, hi = 0x7F800001ull << 32;
    while (hi - lo > 1ull) {
        u64 mid = lo + ((hi - lo) >> 1);
        u32 cl = 0;
#pragma unroll 1
        for (int q = 0; q < 8; ++q) {
            float4 f = xr[q * 64 + lane];
            float vv[4] = {f.x, f.y, f.z, f.w};
#pragma unroll
            for (int c = 0; c < 4; ++c) {
                float v = neg ? -vv[c] : vv[c];
                float pv = v > 0.f ? v : 0.f;
                int idx = q * 256 + lane * 4 + c;
                u64 k = ((u64)__float_as_uint(pv) << 32) | (u64)(u32)(2047 - idx);
                cl += (k >= mid) ? 1u : 0u;
            }
        }
        u32 c = wsum_u(cl);
        if (c >= 32u) { lo = mid; if (c == 32u) break; } else hi = mid;
    }
    float ts = 0.f;
#pragma unroll 1
    for (int q = 0; q < 8; ++q) {
        float4 f = xr[q * 64 + lane];
        float vv[4] = {f.x, f.y, f.z, f.w};
#pragma unroll
        for (int c = 0; c < 4; ++c) {
            float v = neg ? -vv[c] : vv[c];
            float pv = v > 0.f ? v : 0.f;
            int idx = q * 256 + lane * 4 + c;
            u64 k = ((u64)__float_as_uint(pv) << 32) | (u64)(u32)(2047 - idx);
            if (k >= lo) ts += pv;
        }
    }
    ts = wsum_f(ts);
    float tmp = FACTOR * (sum - ts);
    float sgn = neg ? -1.f : 1.f;
#pragma unroll 1
    for (int q = 0; q < 8; ++q) {
        float4 f = xr[q * 64 + lane];
        float vv[4] = {f.x, f.y, f.z, f.w};
#pragma unroll
        for (int c = 0; c < 4; ++c) {
            float v = neg ? -vv[c] : vv[c];
            float pv = v > 0.f ? v : 0.f;
            int idx = q * 256 + lane * 4 + c;
            u64 k = ((u64)__float_as_uint(pv) << 32) | (u64)(u32)(2047 - idx);
            if (k >= lo) atomicAdd(&outrow[idx], sgn * (pv + tmp));
        }
    }
}

__global__ void __launch_bounds__(TPB, 8)
kcomp_kernel(const float* __restrict__ x, float* __restrict__ out) {
    __shared__ u64 s_list[WPB][2][CAP];   // 16 KiB, per-wave private

    const int t    = threadIdx.x;
    const int lane = t & 63;
    const int wave = t >> 6;
    const size_t rbase = (size_t)(blockIdx.x * WPB + wave) * D;

    const float4* xr   = reinterpret_cast<const float4*>(x + rbase);
    float4*       out4 = reinterpret_cast<float4*>(out + rbase);
    float*        outrow = out + rbase;

    // ---- pass 1: load row to regs, per-lane sums + candidate counts
    float rv[32];
    float ps = 0.f, ns = 0.f;
    u32 cP = 0, cN = 0;
#pragma unroll
    for (int q = 0; q < 8; ++q) {
        float4 f = xr[q * 64 + lane];
        rv[q*4+0] = f.x; rv[q*4+1] = f.y; rv[q*4+2] = f.z; rv[q*4+3] = f.w;
#pragma unroll
        for (int c = 0; c < 4; ++c) {
            float v = rv[q*4+c];
            ps += v > 0.f ? v : 0.f;
            ns += v < 0.f ? -v : 0.f;
            cP += v > TH  ? 1u : 0u;
            cN += v < -TH ? 1u : 0u;
        }
    }

    // ---- packed prefix scan for compaction offsets
    u32 packed = cP | (cN << 16);
    u32 inc = packed;
#pragma unroll
    for (int d = 1; d < 64; d <<= 1) {
        u32 n = __shfl_up(inc, (unsigned)d, 64);
        if (lane >= d) inc += n;
    }
    u32 tot  = __shfl(inc, 63, 64);
    u32 exc  = inc - packed;
    u32 totP = tot & 0xffffu, totN = tot >> 16;
    u32 offP = exc & 0xffffu, offN = exc >> 16;
    float sumP = wsum_f(ps), sumN = wsum_f(ns);

    const bool fastP = (totP >= 32u && totP <= CAP);
    const bool fastN = (totN >= 32u && totN <= CAP);
    u64* listP = s_list[wave][0];
    u64* listN = s_list[wave][1];

    // ---- pass 2: compact u64 keys to LDS, store zeros to out (row dies here)
#pragma unroll
    for (int q = 0; q < 8; ++q) {
#pragma unroll
        for (int c = 0; c < 4; ++c) {
            float v = rv[q*4+c];
            u32 fi = (u32)(q * 256 + lane * 4 + c);
            if (fastP && v > TH)
                listP[offP++] = ((u64)__float_as_uint(v)  << 32) | (u64)(2047u - fi);
            if (fastN && v < -TH)
                listN[offN++] = ((u64)__float_as_uint(-v) << 32) | (u64)(2047u - fi);
        }
        out4[q * 64 + lane] = make_float4(0.f, 0.f, 0.f, 0.f);
    }

    // ---- selection per side (list in 4 u64 regs/lane)
    u64 cutP = 0, cutN = 0;
    float PtmpP = 0.f, NtmpN = 0.f;
    u64 p0 = 0, p1 = 0, p2 = 0, p3 = 0, n0 = 0, n1 = 0, n2 = 0, n3 = 0;
    if (fastP) {
        p0 = (lane       < (int)totP) ? listP[lane]       : 0ull;
        p1 = (lane + 64  < (int)totP) ? listP[lane + 64]  : 0ull;
        p2 = (lane + 128 < (int)totP) ? listP[lane + 128] : 0ull;
        p3 = (lane + 192 < (int)totP) ? listP[lane + 192] : 0ull;
        cutP = find_cut(p0, p1, p2, p3);
        float ts = (p0 >= cutP ? valof(p0) : 0.f) + (p1 >= cutP ? valof(p1) : 0.f)
                 + (p2 >= cutP ? valof(p2) : 0.f) + (p3 >= cutP ? valof(p3) : 0.f);
        ts = wsum_f(ts);
        PtmpP = FACTOR * (sumP - ts);
    }
    if (fastN) {
        n0 = (lane       < (int)totN) ? listN[lane]       : 0ull;
        n1 = (lane + 64  < (int)totN) ? listN[lane + 64]  : 0ull;
        n2 = (lane + 128 < (int)totN) ? listN[lane + 128] : 0ull;
        n3 = (lane + 192 < (int)totN) ? listN[lane + 192] : 0ull;
        cutN = find_cut(n0, n1, n2, n3);
        float ts = (n0 >= cutN ? valof(n0) : 0.f) + (n1 >= cutN ? valof(n1) : 0.f)
                 + (n2 >= cutN ? valof(n2) : 0.f) + (n3 >= cutN ? valof(n3) : 0.f);
        ts = wsum_f(ts);
        NtmpN = FACTOR * (sumN - ts);
    }

    // zeros must land before winner scatters (same-wave same-address ordering)
    asm volatile("s_waitcnt vmcnt(0)" ::: "memory");

    const bool anyslow = !(fastP && fastN);
    if (fastP) {
#pragma unroll
        for (int s = 0; s < 4; ++s) {
            u64 k = (s == 0) ? p0 : (s == 1) ? p1 : (s == 2) ? p2 : p3;
            if (k >= cutP) {
                int idx = 2047 - (int)(k & 0x7FFull);
                float val = valof(k) + PtmpP;
                if (anyslow) atomicAdd(&outrow[idx], val);
                else         outrow[idx] = val;
            }
        }
    }
    if (fastN) {
#pragma unroll
        for (int s = 0; s < 4; ++s) {
            u64 k = (s == 0) ? n0 : (s == 1) ? n1 : (s == 2) ? n2 : n3;
            if (k >= cutN) {
                int idx = 2047 - (int)(k & 0x7FFull);
                float val = -(valof(k) + NtmpN);
                if (anyslow) atomicAdd(&outrow[idx], val);
                else         outrow[idx] = val;
            }
        }
    }
    if (!fastP) slow_side(xr, outrow, lane, 0, sumP);
    if (!fastN) slow_side(xr, outrow, lane, 1, sumN);
}

extern "C" void kernel_launch(void* const* d_in, const int* in_sizes, int n_in,
                              void* d_out, int out_size, void* d_ws, size_t ws_size,
                              hipStream_t stream) {
    const float* x = (const float*)d_in[0];
    float* out = (float*)d_out;
    const int rows = in_sizes[0] / D;          // 16384
    kcomp_kernel<<<rows / WPB, TPB, 0, stream>>>(x, out);
}